// Round 3
// baseline (695.134 us; speedup 1.0000x reference)
//
#include <hip/hip_runtime.h>
#include <hip/hip_bf16.h>
#include <math.h>

#define B_SZ    64
#define N_TOK   4096
#define D_FEAT  256
#define K_SLOTS 6
#define H_DIM   64
#define N_IT    3
#define LNKV_BLOCKS 256
#define LNKV_TILES  8   // 256 blocks * 8 tiles * 128 rows = 262144 rows

typedef __attribute__((ext_vector_type(8))) __bf16 bf16x8;
typedef __attribute__((ext_vector_type(4))) __bf16 bf16x4;
typedef __attribute__((ext_vector_type(4))) float  f32x4v;

__device__ __forceinline__ float wave_reduce_sum(float v) {
    #pragma unroll
    for (int off = 32; off > 0; off >>= 1) v += __shfl_xor(v, off, 64);
    return v;
}

// ================= prep: W->bf16 fragment order + small-weight transposes ==========
__global__ __launch_bounds__(256) void prep_kernel(
    const float* __restrict__ Wk, const float* __restrict__ Wv,
    const float* __restrict__ Wq, const float* __restrict__ W_ih,
    const float* __restrict__ W_hh, const float* __restrict__ W1,
    const float* __restrict__ W2,
    __bf16* __restrict__ Wfrag, float* __restrict__ WqT,
    float* __restrict__ WihT, float* __restrict__ WhhT,
    float* __restrict__ W1T, float* __restrict__ W2T)
{
    const int tg = blockIdx.x * 256 + threadIdx.x;
    if (tg < 4096) {
        // Wfrag[ct][ks][lane][j] = Wkv[ct*16+(lane&15)][(lane>>4)*8+ks*32+j]
        const int chunk = tg >> 6, lane = tg & 63;
        const int ct = chunk >> 3, ks = chunk & 7;
        const int outr = ct * 16 + (lane & 15);
        const int dbase = (lane >> 4) * 8 + ks * 32;
        const float* srcw = (outr < 64) ? &Wk[outr * 256] : &Wv[(outr - 64) * 256];
        bf16x8 w8;
        #pragma unroll
        for (int j = 0; j < 8; ++j) w8[j] = (__bf16)srcw[dbase + j];
        *(bf16x8*)&Wfrag[(size_t)tg * 8] = w8;
    } else if (tg < 8192) {
        const int i = tg - 4096;  WqT[i] = Wq[(i & 63) * 64 + (i >> 6)];
    } else if (tg < 20480) {
        const int i = tg - 8192;  WihT[i] = W_ih[(i % 192) * 64 + (i / 192)];
    } else if (tg < 32768) {
        const int i = tg - 20480; WhhT[i] = W_hh[(i % 192) * 64 + (i / 192)];
    } else if (tg < 40960) {
        const int i = tg - 32768; W1T[i] = W1[(i & 127) * 64 + (i >> 7)];
    } else if (tg < 49152) {
        const int i = tg - 40960; W2T[i] = W2[(i & 63) * 128 + (i >> 6)];
    }
}

// ================= Stage 1: fused LN + MFMA -> kbuf bf16 [row][64], vT bf16 [b*64+h][N] ==========
// 256 blocks x 512 threads (8 waves, 2/SIMD). W in LDS once per CU. Per-wave A/C
// slices overlaid; no barriers in the tile loop (all wave-private).
__global__ __launch_bounds__(512, 2) void ln_kv_mfma(
    const float* __restrict__ feat, const float* __restrict__ g,
    const float* __restrict__ bta, const __bf16* __restrict__ Wfrag,
    __bf16* __restrict__ kbuf, __bf16* __restrict__ vT)
{
    __shared__ __align__(16) __bf16 W_lds[32768];       // 64 KB fragment order
    __shared__ __align__(16) __bf16 S_A[8][16 * 272];   // per-wave: A (stride 272) / C overlay (stride 136)

    const int t = threadIdx.x;
    const int lane = t & 63;
    const int w = t >> 6;
    const int m15 = lane & 15, q4 = lane >> 4;

    {   // stage W: 4096 uint4 / 512 threads
        const uint4* src = (const uint4*)Wfrag;
        uint4* dst = (uint4*)W_lds;
        #pragma unroll
        for (int i = 0; i < 8; ++i) dst[i * 512 + t] = src[i * 512 + t];
    }
    __syncthreads();

    const float4 gg = *(const float4*)&g[lane * 4];
    const float4 bb = *(const float4*)&bta[lane * 4];

    const size_t block_row0 = (size_t)blockIdx.x * (LNKV_TILES * 128);
    const int b  = blockIdx.x >> 2;            // 4 blocks per batch
    const int nq = (blockIdx.x & 3) * 1024;    // n-offset within batch

    __bf16* Aw = &S_A[w][0];

    float4 x[16];
    #pragma unroll
    for (int r = 0; r < 16; ++r)
        x[r] = *(const float4*)&feat[(block_row0 + w * 16 + r) * D_FEAT + lane * 4];

    for (int tile = 0; tile < LNKV_TILES; ++tile) {
        const size_t trow0 = block_row0 + (size_t)tile * 128;

        // LN -> A (bf16), wave-private rows
        #pragma unroll
        for (int r = 0; r < 16; ++r) {
            float s1 = x[r].x + x[r].y + x[r].z + x[r].w;
            float s2 = x[r].x * x[r].x + x[r].y * x[r].y + x[r].z * x[r].z + x[r].w * x[r].w;
            s1 = wave_reduce_sum(s1);
            s2 = wave_reduce_sum(s2);
            const float m = s1 * (1.f / 256.f);
            const float inv = rsqrtf(s2 * (1.f / 256.f) - m * m + 1e-5f);
            bf16x4 y;
            y[0] = (__bf16)((x[r].x - m) * inv * gg.x + bb.x);
            y[1] = (__bf16)((x[r].y - m) * inv * gg.y + bb.y);
            y[2] = (__bf16)((x[r].z - m) * inv * gg.z + bb.z);
            y[3] = (__bf16)((x[r].w - m) * inv * gg.w + bb.w);
            *(bf16x4*)&Aw[r * 272 + lane * 4] = y;
        }

        // prefetch next tile
        if (tile + 1 < LNKV_TILES) {
            #pragma unroll
            for (int r = 0; r < 16; ++r)
                x[r] = *(const float4*)&feat[(trow0 + 128 + w * 16 + r) * D_FEAT + lane * 4];
        }

        // A fragments
        bf16x8 af[8];
        #pragma unroll
        for (int ks = 0; ks < 8; ++ks)
            af[ks] = *(const bf16x8*)&Aw[m15 * 272 + q4 * 8 + ks * 32];

        f32x4v acc[8];
        #pragma unroll
        for (int ct = 0; ct < 8; ++ct) acc[ct] = (f32x4v){0.f, 0.f, 0.f, 0.f};
        #pragma unroll
        for (int ks = 0; ks < 8; ++ks) {
            #pragma unroll
            for (int ct = 0; ct < 8; ++ct) {
                const bf16x8 bfr = *(const bf16x8*)&W_lds[((ct * 8 + ks) * 64 + lane) * 8];
                acc[ct] = __builtin_amdgcn_mfma_f32_16x16x32_bf16(af[ks], bfr, acc[ct], 0, 0, 0);
            }
        }

        // C overlay repack (stride 136), wave-private
        #pragma unroll
        for (int ct = 0; ct < 8; ++ct) {
            #pragma unroll
            for (int reg = 0; reg < 4; ++reg)
                Aw[(q4 * 4 + reg) * 136 + ct * 16 + m15] = (__bf16)acc[ct][reg];
        }

        // k store: rows coalesced
        {
            const int r = lane >> 2, seg = lane & 3;
            const bf16x8 k0 = *(const bf16x8*)&Aw[r * 136 + seg * 16];
            const bf16x8 k1 = *(const bf16x8*)&Aw[r * 136 + seg * 16 + 8];
            __bf16* kd = kbuf + (trow0 + w * 16 + r) * 64 + seg * 16;
            *(bf16x8*)&kd[0] = k0;
            *(bf16x8*)&kd[8] = k1;
        }
        // v transposed store: lane = h, column reads (2-way free banks)
        {
            bf16x8 v0, v1;
            #pragma unroll
            for (int i = 0; i < 8; ++i) v0[i] = Aw[i * 136 + 64 + lane];
            #pragma unroll
            for (int i = 0; i < 8; ++i) v1[i] = Aw[(8 + i) * 136 + 64 + lane];
            __bf16* vd = vT + ((size_t)b * 64 + lane) * N_TOK + nq + tile * 128 + w * 16;
            *(bf16x8*)&vd[0] = v0;
            *(bf16x8*)&vd[8] = v1;
        }
    }
}

// ================= fused 3-iteration slot-attention kernel ==========
// 64 blocks (one batch each) x 1024 threads (16 waves). No inter-block traffic.
__global__ __launch_bounds__(1024, 4) void iters_kernel(
    const __bf16* __restrict__ kbuf, const __bf16* __restrict__ vT,
    const float* __restrict__ noise, const float* __restrict__ mu,
    const float* __restrict__ sigma,
    const float* __restrict__ g_slot, const float* __restrict__ b_slot,
    const float* __restrict__ g_mlp, const float* __restrict__ b_mlp,
    const float* __restrict__ WqT,
    const float* __restrict__ WihT, const float* __restrict__ WhhT,
    const float* __restrict__ b_ih, const float* __restrict__ b_hh,
    const float* __restrict__ W1T, const float* __restrict__ b1,
    const float* __restrict__ W2T, const float* __restrict__ b2,
    float* __restrict__ out)
{
    __shared__ float q_lds[16][64];                    // rows 6..15 zeroed
    __shared__ __align__(16) __bf16 p_lds[16][8 * 264]; // per-wave P frags (rows 6,7 zero)
    __shared__ float U_red[16][6][64];
    __shared__ float S_red[16][6][16];
    __shared__ float slots_lds[6][64], x_lds[6][64], m_lds[6][64], s_lds[6][64];
    __shared__ float gi_lds[1152], gh_lds[1152];
    __shared__ float r_lds[6][128];
    __shared__ float S2[6][16];

    const int t = threadIdx.x, lane = t & 63, w = t >> 6;
    const int m15 = lane & 15, q4 = lane >> 4;
    const int b = blockIdx.x;
    const int kk = t >> 6, hh = t & 63;   // (slot, dim) for t<384 paths

    // zero p rows 6,7 (per wave) and q rows 6..15
    for (int i = lane; i < 528; i += 64) p_lds[w][6 * 264 + i] = (__bf16)0.f;
    if (t >= 384) { const int i = t - 384; q_lds[6 + (i >> 6)][i & 63] = 0.f; }

    // slots init + initial q  (s_lds/q path is wave-private per slot)
    if (t < 384) {
        const float sv = mu[hh] + sigma[hh] * noise[(b * K_SLOTS + kk) * 64 + hh];
        slots_lds[kk][hh] = sv;
        const float s1 = wave_reduce_sum(sv), s2 = wave_reduce_sum(sv * sv);
        const float m = s1 * (1.f / 64.f);
        const float inv = rsqrtf(s2 * (1.f / 64.f) - m * m + 1e-5f);
        s_lds[kk][hh] = (sv - m) * inv * g_slot[hh] + b_slot[hh];
        float qv = 0.f;
        #pragma unroll 8
        for (int j = 0; j < 64; ++j) qv += WqT[j * 64 + hh] * s_lds[kk][j];
        q_lds[kk][hh] = qv;
    }
    __syncthreads();

    for (int iter = 0; iter < N_IT; ++iter) {
        // ---- q fragments (A-operand; rows 6..15 are zero) ----
        bf16x8 qf0, qf1;
        #pragma unroll
        for (int j = 0; j < 8; ++j) qf0[j] = (__bf16)q_lds[m15][q4 * 8 + j];
        #pragma unroll
        for (int j = 0; j < 8; ++j) qf1[j] = (__bf16)q_lds[m15][q4 * 8 + 32 + j];

        // ---- phase A: logits via MFMA + softmax over slots; wave owns tokens w*256..+255 ----
        const __bf16* kb = kbuf + ((size_t)b * N_TOK + w * 256) * 64;
        float Sacc[6] = {0.f, 0.f, 0.f, 0.f, 0.f, 0.f};
        #pragma unroll 2
        for (int gi = 0; gi < 16; ++gi) {
            const bf16x8 k0 = *(const bf16x8*)&kb[(gi * 16 + m15) * 64 + q4 * 8];
            const bf16x8 k1 = *(const bf16x8*)&kb[(gi * 16 + m15) * 64 + q4 * 8 + 32];
            f32x4v a = (f32x4v){0.f, 0.f, 0.f, 0.f};
            a = __builtin_amdgcn_mfma_f32_16x16x32_bf16(qf0, k0, a, 0, 0, 0);
            a = __builtin_amdgcn_mfma_f32_16x16x32_bf16(qf1, k1, a, 0, 0, 0);
            const float l4 = __shfl(a[0], m15 + 16, 64);
            const float l5 = __shfl(a[1], m15 + 16, 64);
            if (q4 == 0) {   // token = gi*16 + m15; 6 logits live here
                float l[6] = {a[0] * 0.125f, a[1] * 0.125f, a[2] * 0.125f,
                              a[3] * 0.125f, l4 * 0.125f, l5 * 0.125f};
                float mx = l[0];
                #pragma unroll
                for (int k = 1; k < 6; ++k) mx = fmaxf(mx, l[k]);
                float e[6], ss = 0.f;
                #pragma unroll
                for (int k = 0; k < 6; ++k) { e[k] = __expf(l[k] - mx); ss += e[k]; }
                const float rs = 1.f / ss;
                const int tok = gi * 16 + m15;
                #pragma unroll
                for (int k = 0; k < 6; ++k) {
                    const float p = e[k] * rs;
                    p_lds[w][k * 264 + tok] = (__bf16)p;
                    Sacc[k] += p;
                }
            }
        }

        // ---- phase B: U += P·V via MFMA over this wave's 256 tokens ----
        f32x4v U[4];
        #pragma unroll
        for (int ct = 0; ct < 4; ++ct) U[ct] = (f32x4v){0.f, 0.f, 0.f, 0.f};
        #pragma unroll
        for (int kc = 0; kc < 4; ++kc) {
            const bf16x8 pa0 = *(const bf16x8*)&p_lds[w][(m15 & 7) * 264 + kc * 64 + q4 * 8];
            const bf16x8 pa1 = *(const bf16x8*)&p_lds[w][(m15 & 7) * 264 + kc * 64 + q4 * 8 + 32];
            #pragma unroll
            for (int ct = 0; ct < 4; ++ct) {
                const __bf16* vb = vT + ((size_t)b * 64 + ct * 16 + m15) * N_TOK
                                      + w * 256 + kc * 64 + q4 * 8;
                const bf16x8 v0 = *(const bf16x8*)&vb[0];
                const bf16x8 v1 = *(const bf16x8*)&vb[32];
                U[ct] = __builtin_amdgcn_mfma_f32_16x16x32_bf16(pa0, v0, U[ct], 0, 0, 0);
                U[ct] = __builtin_amdgcn_mfma_f32_16x16x32_bf16(pa1, v1, U[ct], 0, 0, 0);
            }
        }

        // ---- write per-wave partials ----
        #pragma unroll
        for (int ct = 0; ct < 4; ++ct) {
            #pragma unroll
            for (int reg = 0; reg < 4; ++reg) {
                const int row = q4 * 4 + reg;
                if (row < 6) U_red[w][row][ct * 16 + m15] = U[ct][reg];
            }
        }
        if (q4 == 0) {
            #pragma unroll
            for (int k = 0; k < 6; ++k) S_red[w][k][m15] = Sacc[k];
        }
        __syncthreads();

        // ---- reduce partials ----
        float U_tot = 0.f;
        if (t < 384) {
            #pragma unroll
            for (int w16 = 0; w16 < 16; ++w16) U_tot += U_red[w16][kk][hh];
        }
        if (t < 96) {
            const int k2 = t >> 4, m2 = t & 15;
            float s = 0.f;
            #pragma unroll
            for (int w16 = 0; w16 < 16; ++w16) s += S_red[w16][k2][m2];
            S2[k2][m2] = s;
        }
        __syncthreads();
        if (t < 384) {
            float St = 0.f;
            #pragma unroll
            for (int m2 = 0; m2 < 16; ++m2) St += S2[kk][m2];
            x_lds[kk][hh] = U_tot / (St + 1e-8f);
        }
        __syncthreads();

        // ---- GRU matvecs: 1152 outputs over 1024 threads ----
        for (int idx = t; idx < 1152; idx += 1024) {
            const int kq = idx / 192, r = idx % 192;
            float gi = b_ih[r], gh = b_hh[r];
            #pragma unroll 4
            for (int j4 = 0; j4 < 16; ++j4) {
                const float4 xx = *(const float4*)&x_lds[kq][j4 * 4];
                const float4 hv = *(const float4*)&slots_lds[kq][j4 * 4];
                gi += xx.x * WihT[(j4 * 4 + 0) * 192 + r] + xx.y * WihT[(j4 * 4 + 1) * 192 + r]
                    + xx.z * WihT[(j4 * 4 + 2) * 192 + r] + xx.w * WihT[(j4 * 4 + 3) * 192 + r];
                gh += hv.x * WhhT[(j4 * 4 + 0) * 192 + r] + hv.y * WhhT[(j4 * 4 + 1) * 192 + r]
                    + hv.z * WhhT[(j4 * 4 + 2) * 192 + r] + hv.w * WhhT[(j4 * 4 + 3) * 192 + r];
            }
            gi_lds[idx] = gi;
            gh_lds[idx] = gh;
        }
        __syncthreads();

        // ---- gates + LN(mlp) ----
        float hnew = 0.f;
        if (t < 384) {
            const int base = kk * 192;
            const float rg = 1.f / (1.f + __expf(-(gi_lds[base + hh] + gh_lds[base + hh])));
            const float zg = 1.f / (1.f + __expf(-(gi_lds[base + 64 + hh] + gh_lds[base + 64 + hh])));
            const float ng = tanhf(gi_lds[base + 128 + hh] + rg * gh_lds[base + 128 + hh]);
            hnew = (1.f - zg) * ng + zg * slots_lds[kk][hh];
            const float s1 = wave_reduce_sum(hnew), s2 = wave_reduce_sum(hnew * hnew);
            const float m = s1 * (1.f / 64.f);
            const float inv = rsqrtf(s2 * (1.f / 64.f) - m * m + 1e-5f);
            m_lds[kk][hh] = (hnew - m) * inv * g_mlp[hh] + b_mlp[hh];
        }
        __syncthreads();

        // ---- MLP layer 1 ----
        if (t < 768) {
            const int k3 = t >> 7, c = t & 127;
            float a = b1[c];
            #pragma unroll 4
            for (int j4 = 0; j4 < 16; ++j4) {
                const float4 mm = *(const float4*)&m_lds[k3][j4 * 4];
                a += mm.x * W1T[(j4 * 4 + 0) * 128 + c] + mm.y * W1T[(j4 * 4 + 1) * 128 + c]
                   + mm.z * W1T[(j4 * 4 + 2) * 128 + c] + mm.w * W1T[(j4 * 4 + 3) * 128 + c];
            }
            r_lds[k3][c] = fmaxf(a, 0.f);
        }
        __syncthreads();

        // ---- MLP layer 2 + residual (+ next q) ----
        if (t < 384) {
            float o = b2[hh];
            #pragma unroll 4
            for (int c4 = 0; c4 < 32; ++c4) {
                const float4 rr = *(const float4*)&r_lds[kk][c4 * 4];
                o += rr.x * W2T[(c4 * 4 + 0) * 64 + hh] + rr.y * W2T[(c4 * 4 + 1) * 64 + hh]
                   + rr.z * W2T[(c4 * 4 + 2) * 64 + hh] + rr.w * W2T[(c4 * 4 + 3) * 64 + hh];
            }
            const float res = hnew + o;
            slots_lds[kk][hh] = res;
            if (iter == N_IT - 1) {
                out[(b * K_SLOTS + kk) * 64 + hh] = res;
            } else {
                const float s1 = wave_reduce_sum(res), s2 = wave_reduce_sum(res * res);
                const float m = s1 * (1.f / 64.f);
                const float inv = rsqrtf(s2 * (1.f / 64.f) - m * m + 1e-5f);
                s_lds[kk][hh] = (res - m) * inv * g_slot[hh] + b_slot[hh];
                float qv = 0.f;
                #pragma unroll 8
                for (int j = 0; j < 64; ++j) qv += WqT[j * 64 + hh] * s_lds[kk][j];
                q_lds[kk][hh] = qv;
            }
        }
        __syncthreads();
    }
}

extern "C" void kernel_launch(void* const* d_in, const int* in_sizes, int n_in,
                              void* d_out, int out_size, void* d_ws, size_t ws_size,
                              hipStream_t stream) {
    const float* feat      = (const float*)d_in[0];
    const float* noise     = (const float*)d_in[1];
    const float* mu        = (const float*)d_in[2];
    const float* sigma     = (const float*)d_in[3];
    const float* ln_feat_g = (const float*)d_in[4];
    const float* ln_feat_b = (const float*)d_in[5];
    const float* ln_slot_g = (const float*)d_in[6];
    const float* ln_slot_b = (const float*)d_in[7];
    const float* ln_mlp_g  = (const float*)d_in[8];
    const float* ln_mlp_b  = (const float*)d_in[9];
    const float* Wk        = (const float*)d_in[10];
    const float* Wv        = (const float*)d_in[11];
    const float* Wq        = (const float*)d_in[12];
    const float* W_ih      = (const float*)d_in[13];
    const float* W_hh      = (const float*)d_in[14];
    const float* b_ih      = (const float*)d_in[15];
    const float* b_hh      = (const float*)d_in[16];
    const float* W1        = (const float*)d_in[17];
    const float* b1        = (const float*)d_in[18];
    const float* W2        = (const float*)d_in[19];
    const float* b2        = (const float*)d_in[20];
    float* out = (float*)d_out;

    char* p = (char*)d_ws;
    __bf16* kbuf  = (__bf16*)p;  p += (size_t)B_SZ * N_TOK * 64 * 2;   // 32 MB
    __bf16* vTb   = (__bf16*)p;  p += (size_t)B_SZ * 64 * N_TOK * 2;   // 32 MB
    __bf16* Wfrag = (__bf16*)p;  p += 32768 * 2;
    float* WqT    = (float*)p;   p += 4096 * 4;
    float* WihT   = (float*)p;   p += 12288 * 4;
    float* WhhT   = (float*)p;   p += 12288 * 4;
    float* W1T    = (float*)p;   p += 8192 * 4;
    float* W2T    = (float*)p;   p += 8192 * 4;

    hipLaunchKernelGGL(prep_kernel, dim3(192), dim3(256), 0, stream,
                       Wk, Wv, Wq, W_ih, W_hh, W1, W2,
                       Wfrag, WqT, WihT, WhhT, W1T, W2T);
    hipLaunchKernelGGL(ln_kv_mfma, dim3(LNKV_BLOCKS), dim3(512), 0, stream,
                       feat, ln_feat_g, ln_feat_b, Wfrag, kbuf, vTb);
    hipLaunchKernelGGL(iters_kernel, dim3(B_SZ), dim3(1024), 0, stream,
                       kbuf, vTb, noise, mu, sigma,
                       ln_slot_g, ln_slot_b, ln_mlp_g, ln_mlp_b,
                       WqT, WihT, WhhT, b_ih, b_hh, W1T, b1, W2T, b2, out);
}